// Round 8
// baseline (653.662 us; speedup 1.0000x reference)
//
#include <hip/hip_runtime.h>

// Problem constants (match reference setup_inputs)
#define B    64
#define OBJS 2048
#define NTOT (B * OBJS)       // 131072
#define D    256
#define K    2
#define SPB  16               // blocks per scene
#define GRID (B * SPB)        // 1024
#define CH   (OBJS / SPB)     // 128 rows per block
#define RPW  (CH / 4)         // 32 rows per wave

// CO-RESIDENCY INVARIANT (scene barrier is deadlock-free):
//   grid = 1024 = 4 blocks/CU x 256 CUs. __launch_bounds__(256,4) caps VGPR at
//   128 (4 waves/SIMD); LDS ~10.6 KB/block -> 42.4 KB/CU < 160 KB. All blocks
//   co-resident, so a scene's 16 blocks can always all arrive.

// Workspace layout (floats)
#define WS_P1  0                          // GRID*256  phase-A colsum partials
#define WS_UP  (GRID * 256)               // GRID*512  phase-B U partials
#define WS_ZP  (WS_UP + GRID * 512)       // GRID*8    phase-B Z partials
#define WS_E   (WS_ZP + GRID * 8)         // NTOT*2    exp per row (16B aligned)
#define WS_CNT (WS_E + NTOT * 2)          // 128 ints: cnt1[64] (ctx), cnt2[64] (election)

static __device__ __forceinline__ float lrelu02(float v) {
    return v > 0.0f ? v : 0.2f * v;
}

static __device__ __forceinline__ float ldg_agent(const float* p) {
    return __hip_atomic_load(p, __ATOMIC_RELAXED, __HIP_MEMORY_SCOPE_AGENT);
}

__global__ __launch_bounds__(256, 4)
void fused_kernel(const float* __restrict__ x,
                  const int* __restrict__ num_objs,
                  const float* __restrict__ att_scale,
                  const float* __restrict__ att_shared,
                  const float* __restrict__ channel_bias,
                  float* __restrict__ ws,
                  float* __restrict__ out) {
    __shared__ float pl[4 * 576];   // transpose / reduce buffer (9216 B)
    __shared__ float esm[4 * 16];   // per-wave e broadcast
    __shared__ float sctx[D];
    __shared__ float sbt[2];
    __shared__ int   sarr;          // arrival index for finalize election
    __shared__ float zsh[2];

    int blk = blockIdx.x;
    int b = blk >> 4;                    // scene
    int t = threadIdx.x;
    int w = t >> 6, l = t & 63;
    int r = l & 7, s = l >> 3;
    int row0 = blk * CH + w * RPW;
    int* cnt1 = (int*)(ws + WS_CNT) + b;
    int* cnt2 = (int*)(ws + WS_CNT) + 64 + b;

    // ======== phase A: column-sum my 128 rows (x streamed from HBM) ========
    {
        float4 acc = make_float4(0.f, 0.f, 0.f, 0.f);
        const float* px = x + (size_t)row0 * D + 4 * l;
#pragma unroll 8
        for (int j = 0; j < RPW; ++j) {
            float4 v = *(const float4*)(px + (size_t)j * D);
            acc.x += v.x; acc.y += v.y; acc.z += v.z; acc.w += v.w;
        }
        *(float4*)(pl + w * D + 4 * l) = acc;
    }
    __syncthreads();
    if (t < 64) {
        float4 a = ((const float4*)(pl        ))[t];
        float4 e = ((const float4*)(pl +     D))[t];
        float4 f = ((const float4*)(pl + 2 * D))[t];
        float4 g = ((const float4*)(pl + 3 * D))[t];
        float4 sm = make_float4(a.x + e.x + f.x + g.x, a.y + e.y + f.y + g.y,
                                a.z + e.z + f.z + g.z, a.w + e.w + f.w + g.w);
        *(float4*)(ws + WS_P1 + (size_t)blk * D + 4 * t) = sm;
    }
    // bias_term (wave 1 to overlap with wave 0's store above)
    if (w == 1) {
        float4 a = ((const float4*)att_shared)[l];
#pragma unroll
        for (int k = 0; k < K; ++k) {
            float4 cb = ((const float4*)(channel_bias + k * D))[l];
            float v = a.x * cb.x + a.y * cb.y + a.z * cb.z + a.w * cb.w;
#pragma unroll
            for (int m = 32; m > 0; m >>= 1) v += __shfl_xor(v, m);
            if (l == 0) { sbt[0 + k] = v; }
        }
    }

    // ======== scene barrier: all 16 blocks' colsum partials published ========
    __builtin_amdgcn_fence(__ATOMIC_RELEASE, "agent");
    __syncthreads();
    if (t == 0) {
        __hip_atomic_fetch_add(cnt1, 1, __ATOMIC_ACQ_REL, __HIP_MEMORY_SCOPE_AGENT);
        int it = 0;
        while (__hip_atomic_load(cnt1, __ATOMIC_ACQUIRE, __HIP_MEMORY_SCOPE_AGENT) < SPB) {
            __builtin_amdgcn_s_sleep(2);
            if (++it > (1 << 24)) break;   // anti-hang valve (wrong > hung)
        }
    }
    __syncthreads();
    __builtin_amdgcn_fence(__ATOMIC_ACQUIRE, "agent");

    // ctx mean: thread t reduces column t over the scene's 16 partials
    {
        int cnt = num_objs[b]; if (cnt < 1) cnt = 1;
        float inv = 1.0f / (float)cnt;
        float sum = 0.f;
#pragma unroll
        for (int c = 0; c < SPB; ++c)
            sum += ldg_agent(&ws[WS_P1 + (size_t)(b * SPB + c) * D + t]);
        sctx[t] = sum * inv;
    }
    __syncthreads();

    // ======== phase B: batch-8 reduction, x re-read (L3/L2-hot) ========
    float4 a4   = ((const float4*)att_shared)[l];
    float4 ctx4 = *(const float4*)(sctx + 4 * l);
    float bt0 = sbt[0], bt1 = sbt[1];
    float s0 = att_scale[0], s1 = att_scale[1];

    float4 acc0 = make_float4(0.f, 0.f, 0.f, 0.f);
    float4 acc1 = make_float4(0.f, 0.f, 0.f, 0.f);
    float z0 = 0.f, z1 = 0.f;
    float e0c = 0.f, e1c = 0.f;     // lane l<32 captures row (row0+l)'s exps
    float* pw = pl  + w * 576;
    float* ew = esm + w * 16;
    const float* px = x + (size_t)row0 * D + 4 * l;

#pragma unroll
    for (int g = 0; g < 4; ++g) {
        float4 v0 = *(const float4*)(px + (size_t)(g * 8 + 0) * D);
        float4 v1 = *(const float4*)(px + (size_t)(g * 8 + 1) * D);
        float4 v2 = *(const float4*)(px + (size_t)(g * 8 + 2) * D);
        float4 v3 = *(const float4*)(px + (size_t)(g * 8 + 3) * D);
        float4 v4 = *(const float4*)(px + (size_t)(g * 8 + 4) * D);
        float4 v5 = *(const float4*)(px + (size_t)(g * 8 + 5) * D);
        float4 v6 = *(const float4*)(px + (size_t)(g * 8 + 6) * D);
        float4 v7 = *(const float4*)(px + (size_t)(g * 8 + 7) * D);

#define PDOT(V) (lrelu02((V).x + ctx4.x) * a4.x + lrelu02((V).y + ctx4.y) * a4.y \
               + lrelu02((V).z + ctx4.z) * a4.z + lrelu02((V).w + ctx4.w) * a4.w)
        pw[l * 9 + 0] = PDOT(v0); pw[l * 9 + 1] = PDOT(v1);
        pw[l * 9 + 2] = PDOT(v2); pw[l * 9 + 3] = PDOT(v3);
        pw[l * 9 + 4] = PDOT(v4); pw[l * 9 + 5] = PDOT(v5);
        pw[l * 9 + 6] = PDOT(v6); pw[l * 9 + 7] = PDOT(v7);
#undef PDOT
        float tr = 0.f;
#pragma unroll
        for (int q = 0; q < 8; ++q) tr += pw[(s * 8 + q) * 9 + r];
        tr += __shfl_xor(tr, 8);
        tr += __shfl_xor(tr, 16);
        tr += __shfl_xor(tr, 32);      // all lanes: base of row g*8 + (l&7)

        float e0 = __expf((tr + bt0) * s0);
        float e1 = __expf((tr + bt1) * s1);
        if (((l >> 3) & 3) == g) { e0c = e0; e1c = e1; }
        if (l < 8) { ew[2 * l] = e0; ew[2 * l + 1] = e1; }
        float4 E0 = *(const float4*)(ew + 0);
        float4 E1 = *(const float4*)(ew + 4);
        float4 E2 = *(const float4*)(ew + 8);
        float4 E3 = *(const float4*)(ew + 12);
        z0 += E0.x + E0.z + E1.x + E1.z + E2.x + E2.z + E3.x + E3.z;
        z1 += E0.y + E0.w + E1.y + E1.w + E2.y + E2.w + E3.y + E3.w;

#define ACC(V, EA, EB) { acc0.x += (V).x * (EA); acc0.y += (V).y * (EA);      \
                         acc0.z += (V).z * (EA); acc0.w += (V).w * (EA);      \
                         acc1.x += (V).x * (EB); acc1.y += (V).y * (EB);      \
                         acc1.z += (V).z * (EB); acc1.w += (V).w * (EB); }
        ACC(v0, E0.x, E0.y) ACC(v1, E0.z, E0.w)
        ACC(v2, E1.x, E1.y) ACC(v3, E1.z, E1.w)
        ACC(v4, E2.x, E2.y) ACC(v5, E2.z, E2.w)
        ACC(v6, E3.x, E3.y) ACC(v7, E3.z, E3.w)
#undef ACC
    }

    // publish: e rows (lane l<32 owns row row0+l), Z partial, U partial
    if (l < 32) ((float2*)(ws + WS_E))[row0 + l] = make_float2(e0c, e1c);
    if (l == 0) {
        ws[WS_ZP + blk * 8 + w * 2 + 0] = z0;
        ws[WS_ZP + blk * 8 + w * 2 + 1] = z1;
    }
    __syncthreads();
    {
        int base = w * (D * K) + l * 8;
        pl[base + 0] = acc0.x; pl[base + 1] = acc1.x;
        pl[base + 2] = acc0.y; pl[base + 3] = acc1.y;
        pl[base + 4] = acc0.z; pl[base + 5] = acc1.z;
        pl[base + 6] = acc0.w; pl[base + 7] = acc1.w;
    }
    __syncthreads();
    if (t < 128) {
        float4 a = ((const float4*)(pl       ))[t];
        float4 e = ((const float4*)(pl +  512))[t];
        float4 f = ((const float4*)(pl + 1024))[t];
        float4 g = ((const float4*)(pl + 1536))[t];
        float4 s4 = make_float4(a.x + e.x + f.x + g.x, a.y + e.y + f.y + g.y,
                                a.z + e.z + f.z + g.z, a.w + e.w + f.w + g.w);
        *(float4*)(ws + WS_UP + (size_t)blk * (D * K) + 4 * t) = s4;
    }

    // ======== election: 16th arriver of each scene finalizes (no spin) ========
    __builtin_amdgcn_fence(__ATOMIC_RELEASE, "agent");
    __syncthreads();
    if (t == 0)
        sarr = __hip_atomic_fetch_add(cnt2, 1, __ATOMIC_ACQ_REL, __HIP_MEMORY_SCOPE_AGENT);
    __syncthreads();
    if (sarr != SPB - 1) return;          // block-uniform branch
    __builtin_amdgcn_fence(__ATOMIC_ACQUIRE, "agent");

    // ---- finalize scene b (one block, 256 threads) ----
    if (w < 2) {   // waves 0/1 reduce Z for channel 0/1 (64 partials each)
        float v = ldg_agent(&ws[WS_ZP + (b * SPB + (l >> 2)) * 8 + (l & 3) * 2 + w]);
#pragma unroll
        for (int m = 32; m > 0; m >>= 1) v += __shfl_xor(v, m);
        if (l == 0) zsh[w] = v;
    }
    __syncthreads();
    float iz0 = 1.0f / zsh[0], iz1 = 1.0f / zsh[1];

#pragma unroll
    for (int j = t; j < D * K; j += 256) {
        float sum = 0.f;
#pragma unroll
        for (int c = 0; c < SPB; ++c)
            sum += ldg_agent(&ws[WS_UP + (size_t)(b * SPB + c) * (D * K) + j]);
        out[b * (D * K) + j] = sum * ((j & 1) ? iz1 : iz0);
    }
    const float4* E = (const float4*)(ws + WS_E);
    float4* W = (float4*)(out + B * D * K);
#pragma unroll
    for (int i = t; i < OBJS / 2; i += 256) {
        float4 e4 = E[b * (OBJS / 2) + i];
        W[b * (OBJS / 2) + i] = make_float4(e4.x * iz0, e4.y * iz1,
                                            e4.z * iz0, e4.w * iz1);
    }
}

extern "C" void kernel_launch(void* const* d_in, const int* in_sizes, int n_in,
                              void* d_out, int out_size, void* d_ws, size_t ws_size,
                              hipStream_t stream) {
    const float* x            = (const float*)d_in[0];   // [N, D]
    const int*   num_objs     = (const int*)d_in[1];     // [B]
    const float* att_shared   = (const float*)d_in[2];   // [1, D]
    const float* att_scale    = (const float*)d_in[3];   // [K, 1]
    const float* channel_bias = (const float*)d_in[4];   // [K, D]
    float* ws  = (float*)d_ws;
    float* out = (float*)d_out;

    // zero only the barrier/election counters (ws is poisoned 0xAA each replay)
    (void)hipMemsetAsync((char*)d_ws + (size_t)WS_CNT * sizeof(float), 0,
                         128 * sizeof(int), stream);

    fused_kernel<<<GRID, 256, 0, stream>>>(x, num_objs, att_scale, att_shared,
                                           channel_bias, ws, out);
}